// Round 1
// baseline (700.409 us; speedup 1.0000x reference)
//
#include <hip/hip_runtime.h>

#define N_NODES 50000
#define N_EDGES 1600000
#define F_IN 256
#define F_OUT 64
#define ALPHA 0.2f

// ---------------------------------------------------------------------------
// Kernel A: Wh = x @ W  (per-node GEMV, wave-per-node, lane=output feature)
// plus epilogue s_src[i] = dot(Wh[i], a[0:64]), s_dst[i] = dot(Wh[i], a[64:128])
// ---------------------------------------------------------------------------
__global__ __launch_bounds__(256) void gat_gemm(
    const float* __restrict__ x, const float* __restrict__ W,
    const float* __restrict__ a, float* __restrict__ Wh,
    float* __restrict__ s_src, float* __restrict__ s_dst)
{
    const int lane = threadIdx.x & 63;
    const int wave = (int)((blockIdx.x * blockDim.x + threadIdx.x) >> 6);
    const int nw   = (int)((gridDim.x * blockDim.x) >> 6);
    const float a0 = a[lane];
    const float a1 = a[F_OUT + lane];

    for (int i = wave; i < N_NODES; i += nw) {
        const float4* __restrict__ xr = (const float4*)(x + (size_t)i * F_IN);
        float acc = 0.f;
        #pragma unroll 8
        for (int k4 = 0; k4 < F_IN / 4; ++k4) {
            float4 xv = xr[k4];                       // wave-broadcast load
            const float* wr = W + (size_t)k4 * 4 * F_OUT + lane;  // coalesced 256B
            acc = fmaf(xv.x, wr[0 * F_OUT], acc);
            acc = fmaf(xv.y, wr[1 * F_OUT], acc);
            acc = fmaf(xv.z, wr[2 * F_OUT], acc);
            acc = fmaf(xv.w, wr[3 * F_OUT], acc);
        }
        Wh[(size_t)i * F_OUT + lane] = acc;

        // wave-wide reductions for the two attention dots
        float p = acc * a0;
        float q = acc * a1;
        #pragma unroll
        for (int off = 32; off > 0; off >>= 1) {
            p += __shfl_down(p, off);
            q += __shfl_down(q, off);
        }
        if (lane == 0) { s_src[i] = p; s_dst[i] = q; }
    }
}

// ---------------------------------------------------------------------------
// Kernel B: edge pass. Wave handles a batch of 64 edges: coalesced edge loads,
// per-lane edge_e compute + rowsum atomic, then 64 broadcast iterations where
// all 64 lanes gather Wh[dst][lane] and atomically add ee*Wh into out[src].
// ---------------------------------------------------------------------------
__global__ __launch_bounds__(256) void gat_edge(
    const int* __restrict__ edge, const float* __restrict__ Wh,
    const float* __restrict__ s_src, const float* __restrict__ s_dst,
    float* __restrict__ out_acc, float* __restrict__ rowsum)
{
    const int lane = threadIdx.x & 63;
    const int wave = (int)((blockIdx.x * blockDim.x + threadIdx.x) >> 6);
    const int nw   = (int)((gridDim.x * blockDim.x) >> 6);
    const int nbatch = N_EDGES / 64;   // 25000, exact

    for (int b = wave; b < nbatch; b += nw) {
        const int e = b * 64 + lane;
        const int s = edge[e];              // coalesced
        const int d = edge[N_EDGES + e];    // coalesced
        const float score = s_src[s] + s_dst[d];   // 4B random gathers
        const float lr = score > 0.f ? score : ALPHA * score;
        const float ee = __expf(-lr);
        atomicAdd(&rowsum[s], ee);

        #pragma unroll 16
        for (int t = 0; t < 64; ++t) {
            const int   st = __shfl(s, t);
            const int   dt = __shfl(d, t);
            const float et = __shfl(ee, t);
            const float whv = Wh[(size_t)dt * F_OUT + lane];  // coalesced 256B gather
            atomicAdd(&out_acc[(size_t)st * F_OUT + lane], et * whv);  // coalesced 256B atomic
        }
    }
}

// ---------------------------------------------------------------------------
// Kernel C: out = elu(out / rowsum[node])
// ---------------------------------------------------------------------------
__global__ __launch_bounds__(256) void gat_finalize(
    float* __restrict__ out, const float* __restrict__ rowsum)
{
    const int idx = blockIdx.x * blockDim.x + threadIdx.x;
    if (idx < N_NODES * F_OUT) {
        const float v = out[idx] / rowsum[idx >> 6];
        out[idx] = v > 0.f ? v : (__expf(v) - 1.f);
    }
}

extern "C" void kernel_launch(void* const* d_in, const int* in_sizes, int n_in,
                              void* d_out, int out_size, void* d_ws, size_t ws_size,
                              hipStream_t stream) {
    const float* x    = (const float*)d_in[0];
    const int*   edge = (const int*)  d_in[1];
    const float* W    = (const float*)d_in[2];
    const float* a    = (const float*)d_in[3];
    float* out = (float*)d_out;

    float* ws     = (float*)d_ws;
    float* Wh     = ws;                                   // N*64 floats
    float* s_src  = ws + (size_t)N_NODES * F_OUT;         // N floats
    float* s_dst  = s_src + N_NODES;                      // N floats
    float* rowsum = s_dst + N_NODES;                      // N floats

    // zero the accumulators (harness poisons d_out/d_ws with 0xAA)
    hipMemsetAsync(out, 0, (size_t)N_NODES * F_OUT * sizeof(float), stream);
    hipMemsetAsync(rowsum, 0, (size_t)N_NODES * sizeof(float), stream);

    gat_gemm<<<12500, 256, 0, stream>>>(x, W, a, Wh, s_src, s_dst);
    gat_edge<<<6250, 256, 0, stream>>>(edge, Wh, s_src, s_dst, out, rowsum);
    gat_finalize<<<(N_NODES * F_OUT + 255) / 256, 256, 0, stream>>>(out, rowsum);
}

// Round 2
// 644.021 us; speedup vs baseline: 1.0876x; 1.0876x over previous
//
#include <hip/hip_runtime.h>

#define N_NODES 50000
#define N_EDGES 1600000
#define F_IN 256
#define F_OUT 64
#define ALPHA 0.2f

// ---------------------------------------------------------------------------
// Kernel A: Wh = x @ W. Wave handles 4 consecutive nodes (lane = out feature),
// so each 256B W load is reused for 4 nodes (4x less L1 traffic / VMEM inst
// than 1 node/wave). Epilogue: wave reductions for s_src / s_dst.
// ---------------------------------------------------------------------------
__global__ __launch_bounds__(256) void gat_gemm(
    const float* __restrict__ x, const float* __restrict__ W,
    const float* __restrict__ a, float* __restrict__ Wh,
    float* __restrict__ s_src, float* __restrict__ s_dst)
{
    const int lane = threadIdx.x & 63;
    const int wave = (int)((blockIdx.x * blockDim.x + threadIdx.x) >> 6);
    const int nw   = (int)((gridDim.x * blockDim.x) >> 6);
    const float a0 = a[lane];
    const float a1 = a[F_OUT + lane];

    for (int i4 = wave; i4 < N_NODES / 4; i4 += nw) {
        const int node = i4 * 4;
        const float4* __restrict__ x0 = (const float4*)(x + (size_t)node * F_IN);
        const float4* __restrict__ x1 = x0 + (F_IN / 4);
        const float4* __restrict__ x2 = x0 + 2 * (F_IN / 4);
        const float4* __restrict__ x3 = x0 + 3 * (F_IN / 4);
        float acc0 = 0.f, acc1 = 0.f, acc2 = 0.f, acc3 = 0.f;
        #pragma unroll 4
        for (int k4 = 0; k4 < F_IN / 4; ++k4) {
            const float4 v0 = x0[k4];   // wave-uniform broadcast loads
            const float4 v1 = x1[k4];
            const float4 v2 = x2[k4];
            const float4 v3 = x3[k4];
            const float* wr = W + (size_t)k4 * 4 * F_OUT + lane;  // coalesced
            const float w0 = wr[0 * F_OUT];
            const float w1 = wr[1 * F_OUT];
            const float w2 = wr[2 * F_OUT];
            const float w3 = wr[3 * F_OUT];
            acc0 = fmaf(v0.x, w0, fmaf(v0.y, w1, fmaf(v0.z, w2, fmaf(v0.w, w3, acc0))));
            acc1 = fmaf(v1.x, w0, fmaf(v1.y, w1, fmaf(v1.z, w2, fmaf(v1.w, w3, acc1))));
            acc2 = fmaf(v2.x, w0, fmaf(v2.y, w1, fmaf(v2.z, w2, fmaf(v2.w, w3, acc2))));
            acc3 = fmaf(v3.x, w0, fmaf(v3.y, w1, fmaf(v3.z, w2, fmaf(v3.w, w3, acc3))));
        }
        float accs[4] = {acc0, acc1, acc2, acc3};
        #pragma unroll
        for (int j = 0; j < 4; ++j) {
            Wh[(size_t)(node + j) * F_OUT + lane] = accs[j];
            float p = accs[j] * a0;
            float q = accs[j] * a1;
            #pragma unroll
            for (int off = 32; off > 0; off >>= 1) {
                p += __shfl_down(p, off);
                q += __shfl_down(q, off);
            }
            if (lane == 0) { s_src[node + j] = p; s_dst[node + j] = q; }
        }
    }
}

// ---------------------------------------------------------------------------
// Kernel B1: per-edge exp(-leakyrelu(score)) + degree histogram of src
// ---------------------------------------------------------------------------
__global__ __launch_bounds__(256) void gat_hist(
    const int* __restrict__ edge, const float* __restrict__ s_src,
    const float* __restrict__ s_dst, float* __restrict__ eet,
    int* __restrict__ deg)
{
    const int e = blockIdx.x * blockDim.x + threadIdx.x;
    if (e < N_EDGES) {
        const int s = edge[e];
        const int d = edge[N_EDGES + e];
        const float score = s_src[s] + s_dst[d];
        const float lr = score > 0.f ? score : ALPHA * score;
        eet[e] = __expf(-lr);
        atomicAdd(&deg[s], 1);
    }
}

// ---------------------------------------------------------------------------
// Kernel B2: exclusive scan of deg -> row_start (and cursor copy).
// Single block of 1024 threads, each handling a serial chunk of 49.
// ---------------------------------------------------------------------------
__global__ __launch_bounds__(1024) void gat_scan(
    const int* __restrict__ deg, int* __restrict__ row_start,
    int* __restrict__ cursor)
{
    const int T = 1024;
    const int CH = (N_NODES + T - 1) / T;  // 49
    __shared__ int part[1024];
    const int t = threadIdx.x;
    const int base = t * CH;
    int s = 0;
    for (int i = 0; i < CH; ++i) {
        const int idx = base + i;
        if (idx < N_NODES) s += deg[idx];
    }
    part[t] = s;
    __syncthreads();
    for (int off = 1; off < T; off <<= 1) {
        const int v = (t >= off) ? part[t - off] : 0;
        __syncthreads();
        part[t] += v;
        __syncthreads();
    }
    int run = (t > 0) ? part[t - 1] : 0;  // exclusive prefix of this chunk
    for (int i = 0; i < CH; ++i) {
        const int idx = base + i;
        if (idx < N_NODES) {
            row_start[idx] = run;
            cursor[idx] = run;
            run += deg[idx];
        }
    }
    if (t == T - 1) row_start[N_NODES] = part[T - 1];
}

// ---------------------------------------------------------------------------
// Kernel B3: scatter edges into CSR order: col[pos]=dst, eew[pos]=ee
// ---------------------------------------------------------------------------
__global__ __launch_bounds__(256) void gat_scatter(
    const int* __restrict__ edge, const float* __restrict__ eet,
    int* __restrict__ cursor, int* __restrict__ col, float* __restrict__ eew)
{
    const int e = blockIdx.x * blockDim.x + threadIdx.x;
    if (e < N_EDGES) {
        const int s = edge[e];
        const int pos = atomicAdd(&cursor[s], 1);
        col[pos] = edge[N_EDGES + e];
        eew[pos] = eet[e];
    }
}

// ---------------------------------------------------------------------------
// Kernel C: aggregation, wave per node. Lanes cooperatively load 64
// (dst, ee) pairs coalesced, then broadcast each via shfl while all 64
// lanes gather Wh[dst][lane] and accumulate in registers. No atomics.
// Finalize (divide by rowsum + ELU) fused.
// ---------------------------------------------------------------------------
__global__ __launch_bounds__(256) void gat_aggregate(
    const int* __restrict__ row_start, const int* __restrict__ col,
    const float* __restrict__ eew, const float* __restrict__ Wh,
    float* __restrict__ out)
{
    const int lane = threadIdx.x & 63;
    const int wave = (int)((blockIdx.x * blockDim.x + threadIdx.x) >> 6);
    const int nw   = (int)((gridDim.x * blockDim.x) >> 6);

    for (int i = wave; i < N_NODES; i += nw) {
        const int r0 = row_start[i];
        const int r1 = row_start[i + 1];
        float acc = 0.f, rsum = 0.f;
        for (int b = r0; b < r1; b += 64) {
            int m = r1 - b;
            if (m > 64) m = 64;
            int c = 0;
            float w = 0.f;
            if (lane < m) { c = col[b + lane]; w = eew[b + lane]; }  // coalesced
            for (int t = 0; t < m; ++t) {
                const int   dt = __shfl(c, t);
                const float et = __shfl(w, t);
                acc = fmaf(et, Wh[(size_t)dt * F_OUT + lane], acc);  // coalesced 256B gather
                rsum += et;
            }
        }
        const float v = acc / rsum;
        out[(size_t)i * F_OUT + lane] = v > 0.f ? v : (__expf(v) - 1.f);
    }
}

extern "C" void kernel_launch(void* const* d_in, const int* in_sizes, int n_in,
                              void* d_out, int out_size, void* d_ws, size_t ws_size,
                              hipStream_t stream) {
    const float* x    = (const float*)d_in[0];
    const int*   edge = (const int*)  d_in[1];
    const float* W    = (const float*)d_in[2];
    const float* a    = (const float*)d_in[3];
    float* out = (float*)d_out;

    float* ws        = (float*)d_ws;
    float* Wh        = ws;                                  // 3,200,000 f
    float* s_src     = Wh + (size_t)N_NODES * F_OUT;        // 50,000 f
    float* s_dst     = s_src + N_NODES;                     // 50,000 f
    float* eet       = s_dst + N_NODES;                     // 1,600,000 f
    int*   col       = (int*)(eet + N_EDGES);               // 1,600,000 i
    float* eew       = (float*)(col + N_EDGES);             // 1,600,000 f
    int*   deg       = (int*)(eew + N_EDGES);               // 50,000 i
    int*   row_start = deg + N_NODES;                       // 50,001 i
    int*   cursor    = row_start + N_NODES + 1;             // 50,000 i

    hipMemsetAsync(deg, 0, (size_t)N_NODES * sizeof(int), stream);

    gat_gemm<<<3125, 256, 0, stream>>>(x, W, a, Wh, s_src, s_dst);
    gat_hist<<<N_EDGES / 256, 256, 0, stream>>>(edge, s_src, s_dst, eet, deg);
    gat_scan<<<1, 1024, 0, stream>>>(deg, row_start, cursor);
    gat_scatter<<<N_EDGES / 256, 256, 0, stream>>>(edge, eet, cursor, col, eew);
    gat_aggregate<<<3125, 256, 0, stream>>>(row_start, col, eew, Wh, out);
}

// Round 3
// 459.984 us; speedup vs baseline: 1.5227x; 1.4001x over previous
//
#include <hip/hip_runtime.h>

#define N_NODES 50000
#define N_EDGES 1600000
#define F_IN 256
#define F_OUT 64
#define ALPHA 0.2f

#define SCAN_BLOCKS 250
#define SCAN_CHUNK  200   // 250*200 = 50000 exact

// ---------------------------------------------------------------------------
// Kernel A: Wh = x @ W with W staged in LDS (64KB, loaded once per block).
// 8 nodes per wave iteration, lane = out feature. W reads from LDS are
// bank-conflict-free (addr%32 == lane%32 -> 2-way aliasing, free on CDNA4).
// Epilogue: wave reductions for s_src / s_dst.
// ---------------------------------------------------------------------------
__global__ __launch_bounds__(256) void gat_gemm(
    const float* __restrict__ x, const float* __restrict__ W,
    const float* __restrict__ a, float* __restrict__ Wh,
    float* __restrict__ s_src, float* __restrict__ s_dst)
{
    __shared__ float Wl[F_IN * F_OUT];  // 64 KB
    const int t = threadIdx.x;
    {
        const float4* __restrict__ Wv = (const float4*)W;
        float4* Wlv = (float4*)Wl;
        #pragma unroll
        for (int i = 0; i < (F_IN * F_OUT / 4) / 256; ++i)
            Wlv[t + i * 256] = Wv[t + i * 256];
    }
    __syncthreads();

    const int lane = t & 63;
    const int wave = blockIdx.x * 4 + (t >> 6);
    const int nw   = gridDim.x * 4;
    const float a0 = a[lane];
    const float a1 = a[F_OUT + lane];

    const int NPW = 8;
    for (int g = wave; g < N_NODES / NPW; g += nw) {
        const int node = g * NPW;
        const float4* __restrict__ xr = (const float4*)(x + (size_t)node * F_IN);
        float acc[NPW];
        #pragma unroll
        for (int j = 0; j < NPW; ++j) acc[j] = 0.f;

        #pragma unroll 2
        for (int k4 = 0; k4 < F_IN / 4; ++k4) {
            float4 xv[NPW];
            #pragma unroll
            for (int j = 0; j < NPW; ++j) xv[j] = xr[j * (F_IN / 4) + k4];
            const float w0 = Wl[(4 * k4 + 0) * F_OUT + lane];
            const float w1 = Wl[(4 * k4 + 1) * F_OUT + lane];
            const float w2 = Wl[(4 * k4 + 2) * F_OUT + lane];
            const float w3 = Wl[(4 * k4 + 3) * F_OUT + lane];
            #pragma unroll
            for (int j = 0; j < NPW; ++j)
                acc[j] = fmaf(xv[j].x, w0, fmaf(xv[j].y, w1,
                         fmaf(xv[j].z, w2, fmaf(xv[j].w, w3, acc[j]))));
        }
        #pragma unroll
        for (int j = 0; j < NPW; ++j) {
            Wh[(size_t)(node + j) * F_OUT + lane] = acc[j];
            float p = acc[j] * a0;
            float q = acc[j] * a1;
            #pragma unroll
            for (int off = 32; off > 0; off >>= 1) {
                p += __shfl_down(p, off);
                q += __shfl_down(q, off);
            }
            if (lane == 0) { s_src[node + j] = p; s_dst[node + j] = q; }
        }
    }
}

// ---------------------------------------------------------------------------
// Kernel B1: degree histogram of src (only reads the src half of edge)
// ---------------------------------------------------------------------------
__global__ __launch_bounds__(256) void gat_hist(
    const int* __restrict__ edge, int* __restrict__ deg)
{
    const int e = blockIdx.x * blockDim.x + threadIdx.x;
    if (e < N_EDGES) atomicAdd(&deg[edge[e]], 1);
}

// ---------------------------------------------------------------------------
// Kernels B2a/b/c: hierarchical exclusive scan of deg -> row_start, cursor
// ---------------------------------------------------------------------------
__global__ __launch_bounds__(256) void scan_part(
    const int* __restrict__ deg, int* __restrict__ part)
{
    __shared__ int sm[256];
    const int t = threadIdx.x;
    const int base = blockIdx.x * SCAN_CHUNK;
    sm[t] = (t < SCAN_CHUNK) ? deg[base + t] : 0;
    __syncthreads();
    #pragma unroll
    for (int off = 128; off > 0; off >>= 1) {
        if (t < off) sm[t] += sm[t + off];
        __syncthreads();
    }
    if (t == 0) part[blockIdx.x] = sm[0];
}

__global__ __launch_bounds__(256) void scan_mid(
    const int* __restrict__ part, int* __restrict__ partscan,
    int* __restrict__ row_start)
{
    __shared__ int sm[256];
    const int t = threadIdx.x;
    const int v = (t < SCAN_BLOCKS) ? part[t] : 0;
    sm[t] = v;
    __syncthreads();
    #pragma unroll
    for (int off = 1; off < 256; off <<= 1) {
        const int u = (t >= off) ? sm[t - off] : 0;
        __syncthreads();
        sm[t] += u;
        __syncthreads();
    }
    if (t < SCAN_BLOCKS) partscan[t] = sm[t] - v;          // exclusive
    if (t == SCAN_BLOCKS - 1) row_start[N_NODES] = sm[t];  // total = N_EDGES
}

__global__ __launch_bounds__(256) void scan_final(
    const int* __restrict__ deg, const int* __restrict__ partscan,
    int* __restrict__ row_start, int* __restrict__ cursor)
{
    __shared__ int sm[256];
    const int t = threadIdx.x;
    const int base = blockIdx.x * SCAN_CHUNK;
    const int v = (t < SCAN_CHUNK) ? deg[base + t] : 0;
    sm[t] = v;
    __syncthreads();
    #pragma unroll
    for (int off = 1; off < 256; off <<= 1) {
        const int u = (t >= off) ? sm[t - off] : 0;
        __syncthreads();
        sm[t] += u;
        __syncthreads();
    }
    if (t < SCAN_CHUNK) {
        const int excl = sm[t] - v + partscan[blockIdx.x];
        row_start[base + t] = excl;
        cursor[base + t] = excl;
    }
}

// ---------------------------------------------------------------------------
// Kernel B3: scatter edges into CSR, computing ee inline and packing
// (dst, ee) into a single 8B int2 store (half the scattered-line traffic
// of two separate 4B stores).
// ---------------------------------------------------------------------------
__global__ __launch_bounds__(256) void gat_scatter(
    const int* __restrict__ edge, const float* __restrict__ s_src,
    const float* __restrict__ s_dst, int* __restrict__ cursor,
    int2* __restrict__ csr)
{
    const int e = blockIdx.x * blockDim.x + threadIdx.x;
    if (e < N_EDGES) {
        const int s = edge[e];
        const int d = edge[N_EDGES + e];
        const float score = s_src[s] + s_dst[d];   // 4B gathers, L2-resident tables
        const float lr = score > 0.f ? score : ALPHA * score;
        const float ee = __expf(-lr);
        const int pos = atomicAdd(&cursor[s], 1);
        csr[pos] = make_int2(d, __float_as_int(ee));
    }
}

// ---------------------------------------------------------------------------
// Kernel C: aggregation, wave per node, register accumulation, no atomics.
// Finalize (divide + ELU) fused.
// ---------------------------------------------------------------------------
__global__ __launch_bounds__(256) void gat_aggregate(
    const int* __restrict__ row_start, const int2* __restrict__ csr,
    const float* __restrict__ Wh, float* __restrict__ out)
{
    const int lane = threadIdx.x & 63;
    const int wave = (int)((blockIdx.x * blockDim.x + threadIdx.x) >> 6);
    const int nw   = (int)((gridDim.x * blockDim.x) >> 6);

    for (int i = wave; i < N_NODES; i += nw) {
        const int r0 = row_start[i];
        const int r1 = row_start[i + 1];
        float acc = 0.f, rsum = 0.f;
        for (int b = r0; b < r1; b += 64) {
            int m = r1 - b;
            if (m > 64) m = 64;
            int2 cw = make_int2(0, 0);
            if (lane < m) cw = csr[b + lane];   // coalesced 8B
            for (int t = 0; t < m; ++t) {
                const int   dt = __shfl(cw.x, t);
                const float et = __int_as_float(__shfl(cw.y, t));
                acc = fmaf(et, Wh[(size_t)dt * F_OUT + lane], acc);  // coalesced 256B gather
                rsum += et;
            }
        }
        const float v = acc / rsum;
        out[(size_t)i * F_OUT + lane] = v > 0.f ? v : (__expf(v) - 1.f);
    }
}

extern "C" void kernel_launch(void* const* d_in, const int* in_sizes, int n_in,
                              void* d_out, int out_size, void* d_ws, size_t ws_size,
                              hipStream_t stream) {
    const float* x    = (const float*)d_in[0];
    const int*   edge = (const int*)  d_in[1];
    const float* W    = (const float*)d_in[2];
    const float* a    = (const float*)d_in[3];
    float* out = (float*)d_out;

    float* ws        = (float*)d_ws;
    float* Wh        = ws;                                   // 3,200,000 f
    int2*  csr       = (int2*)(Wh + (size_t)N_NODES * F_OUT); // 1.6M int2 (8B-aligned)
    float* s_src     = (float*)(csr + N_EDGES);              // 50,000 f
    float* s_dst     = s_src + N_NODES;                      // 50,000 f
    int*   deg       = (int*)(s_dst + N_NODES);              // 50,000 i
    int*   part      = deg + N_NODES;                        // 256 i
    int*   partscan  = part + 256;                           // 256 i
    int*   row_start = partscan + 256;                       // 50,001 i
    int*   cursor    = row_start + N_NODES + 1;              // 50,000 i

    hipMemsetAsync(deg, 0, (size_t)N_NODES * sizeof(int), stream);

    gat_gemm<<<512, 256, 0, stream>>>(x, W, a, Wh, s_src, s_dst);
    gat_hist<<<N_EDGES / 256, 256, 0, stream>>>(edge, deg);
    scan_part<<<SCAN_BLOCKS, 256, 0, stream>>>(deg, part);
    scan_mid<<<1, 256, 0, stream>>>(part, partscan, row_start);
    scan_final<<<SCAN_BLOCKS, 256, 0, stream>>>(deg, partscan, row_start, cursor);
    gat_scatter<<<N_EDGES / 256, 256, 0, stream>>>(edge, s_src, s_dst, cursor, csr);
    gat_aggregate<<<3125, 256, 0, stream>>>(row_start, csr, Wh, out);
}